// Round 10
// baseline (329.588 us; speedup 1.0000x reference)
//
#include <hip/hip_runtime.h>
#include <hip/hip_bf16.h>
#include <stdint.h>

typedef short short8 __attribute__((ext_vector_type(8)));
typedef float f32x4 __attribute__((ext_vector_type(4)));

#define M_Q   25088   // B*H*W = 512*49
#define M_S   3136    // NS*HS*WS = 16*196
#define IN_   12544
#define LOG2E  1.44269504f
#define SHIFT2 57.7078016f   // 40 * log2(e); exp(l-40) == exp2(l*log2e - SHIFT2)
#define NZ    4       // attention key-split
#define FZ    8       // fc6 K-split
#define KSTR  136     // K-LDS row stride (ushorts): 272B = 4-bank shift per row
#define PSTR  40      // P-LDS row stride (ushorts): >=32 (row length!) + pad

__device__ __forceinline__ ushort f2bf(float f) {
  union { float f; uint32_t u; } v; v.f = f;
  uint32_t r = v.u + 0x7fffu + ((v.u >> 16) & 1u);
  return (ushort)(r >> 16);
}
// cheap round-half-up; used only for P (positive values)
__device__ __forceinline__ ushort f2bf_fast(float f) {
  union { float f; uint32_t u; } v; v.f = f;
  return (ushort)((v.u + 0x8000u) >> 16);
}
__device__ __forceinline__ float bf2f(ushort u) {
  union { uint32_t u; float f; } v; v.u = ((uint32_t)u) << 16;
  return v.f;
}
__device__ __forceinline__ f32x4 mfma16(short8 a, short8 b, f32x4 c) {
  return __builtin_amdgcn_mfma_f32_16x16x32_bf16(a, b, c, 0, 0, 0);
}

// ---------------- coalesced transpose+pack: [B][256][P] f32 -> [B*P][256] hi/lo bf16
__global__ __launch_bounds__(256) void transpose_pack(
    const float* __restrict__ src, ushort* __restrict__ hi,
    ushort* __restrict__ lo, int P) {
  const int b = blockIdx.x;
  const int p0 = blockIdx.y * 49;
  const int w = threadIdx.x >> 6, l = threadIdx.x & 63;
  if (l >= 49) return;
  const int p = p0 + l;
  const float* sb = src + (size_t)b * 256 * P + p;
  const size_t orow = ((size_t)b * P + p) * 256;
  const int ch0 = blockIdx.z * 2;
#pragma unroll
  for (int ch = 0; ch < 2; ++ch) {
    const int c0 = ((ch0 + ch) * 4 + w) * 8;
    short8 h8, l8;
#pragma unroll
    for (int j = 0; j < 8; ++j) {
      float v = sb[(size_t)(c0 + j) * P];
      ushort h = f2bf(v);
      h8[j] = (short)h;
      l8[j] = (short)f2bf(v - bf2f(h));
    }
    *(short8*)(hi + orow + c0) = h8;
    *(short8*)(lo + orow + c0) = l8;
  }
}

// stack conv weights [128,256]+[128,256] -> [256,256] hi/lo, plus biases
__global__ void pack_w(const float* __restrict__ Wqv, const float* __restrict__ Wqk,
                       const float* __restrict__ bqv, const float* __restrict__ bqk,
                       const float* __restrict__ Wsv, const float* __restrict__ Wsk,
                       const float* __restrict__ bsv, const float* __restrict__ bsk,
                       ushort* __restrict__ Wq_h, ushort* __restrict__ Wq_l, float* __restrict__ biasq,
                       ushort* __restrict__ Ws_h, ushort* __restrict__ Ws_l, float* __restrict__ biass) {
  int idx = blockIdx.x * 256 + threadIdx.x;
  if (idx < 65536) {
    int n = idx >> 8;
    const float* W = (n < 128) ? (Wqv + n * 256) : (Wqk + (n - 128) * 256);
    float v = W[idx & 255];
    ushort h = f2bf(v);
    Wq_h[idx] = h; Wq_l[idx] = f2bf(v - bf2f(h));
  } else if (idx < 131072) {
    int j = idx - 65536;
    int n = j >> 8;
    const float* W = (n < 128) ? (Wsv + n * 256) : (Wsk + (n - 128) * 256);
    float v = W[j & 255];
    ushort h = f2bf(v);
    Ws_h[j] = h; Ws_l[j] = f2bf(v - bf2f(h));
  } else if (idx < 131328) {
    int n = idx - 131072;
    biasq[n] = (n < 128) ? bqv[n] : bqk[n - 128];
  } else if (idx < 131584) {
    int n = idx - 131328;
    biass[n] = (n < 128) ? bsv[n] : bsk[n - 128];
  }
}

// W6 [n][c*49+p] f32 -> W6p [n][p*256+c] bf16 via LDS tile (both sides coalesced)
__global__ __launch_bounds__(256) void pack_w6(
    const float* __restrict__ W6c, const float* __restrict__ W6r,
    ushort* __restrict__ W6p) {
  __shared__ ushort tile[IN_];
  const int n = blockIdx.x;
  const float* src = (n < 1024) ? (W6c + (size_t)n * IN_)
                                : (W6r + (size_t)(n - 1024) * IN_);
  ushort* dst = W6p + (size_t)n * IN_;
#pragma unroll 7
  for (int j = 0; j < 49; ++j) {
    int i = j * 256 + threadIdx.x;
    tile[i] = f2bf(src[i]);
  }
  __syncthreads();
#pragma unroll 7
  for (int j = 0; j < 49; ++j) {
    int o = j * 256 + threadIdx.x;
    int c = o & 255, p = o >> 8;
    dst[o] = tile[c * 49 + p];
  }
}

// W7 -> bf16 [2048][1024] (xc rows then xr rows)
__global__ void pack_w7(const float* __restrict__ W7c, const float* __restrict__ W7r,
                        ushort* __restrict__ W7p) {
  int idx = blockIdx.x * 256 + threadIdx.x;  // exactly 2048*1024
  float v = (idx < 1048576) ? W7c[idx] : W7r[idx - 1048576];
  W7p[idx] = f2bf(v);
}

// ---------------- conv GEMM Q (unsplit, acc[16]) ------------------------------
// qv half (n<128): 2-term split-bf16 -> fuse token-major.
// qk half (n>=128): 3-term (f32-accurate) -> qk_h bf16 scaled by log2(e).
__global__ __launch_bounds__(256) void gemm_conv_q(
    const ushort* __restrict__ Ah, const ushort* __restrict__ Al,
    const ushort* __restrict__ Bh, const ushort* __restrict__ Bl,
    const float* __restrict__ bias, ushort* __restrict__ fuse,
    ushort* __restrict__ qk_h) {
  const int lane = threadIdx.x & 63, wv = threadIdx.x >> 6;
  const int r = lane & 15, g = lane >> 4;
  const int row0 = blockIdx.x * 64 + wv * 16;
  const ushort* arh = Ah + (size_t)(row0 + r) * 256 + g * 8;
  const ushort* arl = Al + (size_t)(row0 + r) * 256 + g * 8;
  f32x4 acc[16];
#pragma unroll
  for (int i = 0; i < 16; ++i) acc[i] = f32x4{0.f, 0.f, 0.f, 0.f};
#pragma unroll
  for (int kc = 0; kc < 8; ++kc) {
    short8 ah = *(const short8*)(arh + kc * 32);
    short8 al = *(const short8*)(arl + kc * 32);
    const ushort* bbh = Bh + r * 256 + kc * 32 + g * 8;
    const ushort* bbl = Bl + r * 256 + kc * 32 + g * 8;
#pragma unroll
    for (int nt = 0; nt < 16; ++nt) {
      short8 bh = *(const short8*)(bbh + nt * 16 * 256);
      acc[nt] = mfma16(ah, bh, acc[nt]);
      acc[nt] = mfma16(al, bh, acc[nt]);
      if (nt >= 8) {  // qk half needs full accuracy: + ah*bl
        short8 bl = *(const short8*)(bbl + nt * 16 * 256);
        acc[nt] = mfma16(ah, bl, acc[nt]);
      }
    }
  }
  const int qr = row0 + g * 4;
#pragma unroll
  for (int nt = 0; nt < 16; ++nt) {
    int n = nt * 16 + r;
    float bs = bias[n];
#pragma unroll
    for (int e = 0; e < 4; ++e) {
      float v = acc[nt][e] + bs;
      int q = qr + e;
      if (nt < 8) {
        int b = q / 49, p = q - b * 49;
        fuse[(size_t)b * IN_ + p * 256 + n] = f2bf(v);
      } else {
        qk_h[(size_t)q * 128 + (n - 128)] = f2bf(v * LOG2E);
      }
    }
  }
}

// S variant (n-split x2): nb==0 -> svT (2-term); nb==1 -> sk_h (3-term, f32-acc)
__global__ __launch_bounds__(256) void gemm_conv_s(
    const ushort* __restrict__ Ah, const ushort* __restrict__ Al,
    const ushort* __restrict__ Bh, const ushort* __restrict__ Bl,
    const float* __restrict__ bias, ushort* __restrict__ svT,
    ushort* __restrict__ sk_h) {
  const int lane = threadIdx.x & 63, wv = threadIdx.x >> 6;
  const int r = lane & 15, g = lane >> 4;
  const int row0 = blockIdx.x * 64 + wv * 16;
  const int nb = blockIdx.y;
  const ushort* arh = Ah + (size_t)(row0 + r) * 256 + g * 8;
  const ushort* arl = Al + (size_t)(row0 + r) * 256 + g * 8;
  f32x4 acc[8];
#pragma unroll
  for (int i = 0; i < 8; ++i) acc[i] = f32x4{0.f, 0.f, 0.f, 0.f};
#pragma unroll
  for (int kc = 0; kc < 8; ++kc) {
    short8 ah = *(const short8*)(arh + kc * 32);
    short8 al = *(const short8*)(arl + kc * 32);
    const ushort* bbh = Bh + (size_t)(nb * 128 + r) * 256 + kc * 32 + g * 8;
    const ushort* bbl = Bl + (size_t)(nb * 128 + r) * 256 + kc * 32 + g * 8;
#pragma unroll
    for (int nt = 0; nt < 8; ++nt) {
      short8 bh = *(const short8*)(bbh + nt * 16 * 256);
      acc[nt] = mfma16(ah, bh, acc[nt]);
      acc[nt] = mfma16(al, bh, acc[nt]);
      if (nb == 1) {
        short8 bl = *(const short8*)(bbl + nt * 16 * 256);
        acc[nt] = mfma16(ah, bl, acc[nt]);
      }
    }
  }
  const int qr = row0 + g * 4;
#pragma unroll
  for (int nt = 0; nt < 8; ++nt) {
    int nl = nt * 16 + r;
    float bs = bias[nb * 128 + nl];
#pragma unroll
    for (int e = 0; e < 4; ++e) {
      float v = acc[nt][e] + bs;
      int k = qr + e;
      if (nb == 0) {
        svT[(size_t)nl * M_S + k] = f2bf(v);
      } else {
        sk_h[(size_t)k * 128 + nl] = f2bf(v);
      }
    }
  }
}

// ---------------- fused attention: dbuf LDS, 16 q-rows/wave --------------------
// block = 256 thr = 4 waves; 64 q-rows/block; key chunk z of NZ.
// grid (392, NZ) = 1568 blocks -> ~6 blocks/CU queued, 4 resident (LDS cap).
#define LOAD_TILE(T)                                                            \
  do {                                                                          \
    const int kb_ = (T) * 32;                                                   \
    pkh0 = *(const short8*)(Kh + (size_t)(kb_ + row0s) * 128 + c8s * 8);        \
    pkh1 = *(const short8*)(Kh + (size_t)(kb_ + row0s + 16) * 128 + c8s * 8);   \
    pv0  = *(const short8*)(Vt + (size_t)cvs * M_S + kb_ + kc2s * 8);           \
    pv1  = *(const short8*)(Vt + (size_t)(cvs + 64) * M_S + kb_ + kc2s * 8);    \
  } while (0)
#define PUBLISH(B)                                                              \
  do {                                                                          \
    *(short8*)(&khs[B][kloff0]) = pkh0;                                         \
    *(short8*)(&khs[B][kloff1]) = pkh1;                                         \
    *(short8*)(&vvs[B][voff0]) = pv0;                                           \
    *(short8*)(&vvs[B][voff1]) = pv1;                                           \
  } while (0)

__global__ __launch_bounds__(256) void attn_kernel(
    const ushort* __restrict__ Qh, const ushort* __restrict__ Kh,
    const ushort* __restrict__ Vt, float* __restrict__ pnum,
    float* __restrict__ pden) {
  __shared__ ushort khs[2][32 * KSTR];
  __shared__ ushort vvs[2][128 * 32];
  __shared__ ushort plds[4][16 * PSTR];
  const int tid = threadIdx.x;
  const int w = tid >> 6, lane = tid & 63;
  const int r = lane & 15, g = lane >> 4;
  const int q0 = blockIdx.x * 64 + w * 16;
  const int z = blockIdx.y;
  const int t0 = z * 24 + (z < 2 ? z : 2);
  const int tn = 24 + (z < 2 ? 1 : 0);
  ushort* pw = plds[w];

  const int row0s = tid >> 4, c8s = tid & 15;
  const int cvs = tid >> 2, kc2s = tid & 3;
  const int kloff0 = row0s * KSTR + c8s * 8;
  const int kloff1 = (row0s + 16) * KSTR + c8s * 8;
  const int voff0 = cvs * 32 + kc2s * 8;
  const int voff1 = (cvs + 64) * 32 + kc2s * 8;

  short8 aq[4];
#pragma unroll
  for (int kc = 0; kc < 4; ++kc)
    aq[kc] = *(const short8*)(Qh + (size_t)(q0 + r) * 128 + kc * 32 + g * 8);

  f32x4 acc[8];
#pragma unroll
  for (int ct = 0; ct < 8; ++ct) acc[ct] = f32x4{0.f, 0.f, 0.f, 0.f};
  float den[4];
#pragma unroll
  for (int e = 0; e < 4; ++e) den[e] = 0.f;

  short8 pkh0, pkh1, pv0, pv1;
  LOAD_TILE(t0);
  PUBLISH(0);
  if (tn > 1) LOAD_TILE(t0 + 1);
  __syncthreads();

  for (int i = 0; i < tn; ++i) {
    const int b = i & 1;
    if (i + 1 < tn) {
      PUBLISH(b ^ 1);                 // buf^1 last read at barrier ending i-1
      if (i + 2 < tn) LOAD_TILE(t0 + i + 2);
    }
    // ---- QK^T from LDS buf b (bf16 x bf16) ----
    f32x4 lg[2];
#pragma unroll
    for (int kt = 0; kt < 2; ++kt) {
      const int kbase = (kt * 16 + r) * KSTR;
      f32x4 c = f32x4{0.f, 0.f, 0.f, 0.f};
#pragma unroll
      for (int kc = 0; kc < 4; ++kc) {
        short8 bh = *(const short8*)(&khs[b][kbase + (kc * 4 + g) * 8]);
        c = mfma16(aq[kc], bh, c);
      }
      lg[kt] = c;
    }
    // ---- exp2 -> P (per-wave LDS slice) ----
#pragma unroll
    for (int kt = 0; kt < 2; ++kt)
#pragma unroll
      for (int e = 0; e < 4; ++e) {
        float p = __builtin_amdgcn_exp2f(lg[kt][e] - SHIFT2);
        den[e] += p;
        pw[(g * 4 + e) * PSTR + kt * 16 + r] = f2bf_fast(p);
      }
    // ---- PV from LDS ----
    short8 pf = *(const short8*)(pw + r * PSTR + g * 8);
#pragma unroll
    for (int ct = 0; ct < 8; ++ct) {
      short8 vf = *(const short8*)(&vvs[b][(ct * 16 + r) * 32 + g * 8]);
      acc[ct] = mfma16(pf, vf, acc[ct]);
    }
    __syncthreads();
  }

#pragma unroll
  for (int e = 0; e < 4; ++e) {
    float d = den[e];
    d += __shfl_xor(d, 1);
    d += __shfl_xor(d, 2);
    d += __shfl_xor(d, 4);
    d += __shfl_xor(d, 8);
    den[e] = d;
  }
#pragma unroll
  for (int ct = 0; ct < 8; ++ct)
#pragma unroll
    for (int e = 0; e < 4; ++e) {
      int q = q0 + g * 4 + e;
      int c = ct * 16 + r;
      pnum[((size_t)z * M_Q + q) * 128 + c] = acc[ct][e];
    }
  if (r == 0) {
#pragma unroll
    for (int e = 0; e < 4; ++e)
      pden[(size_t)z * M_Q + q0 + g * 4 + e] = den[e];
  }
}

// combine key-split partials -> att half of fuse (token-major, coalesced)
typedef ushort ushort4v __attribute__((ext_vector_type(4)));
__global__ void attn_reduce(const float* __restrict__ pnum, const float* __restrict__ pden,
                            ushort* __restrict__ fuse) {
  int idx = blockIdx.x * 256 + threadIdx.x;  // exactly 25088*32 (c-quads)
  int q = idx >> 5;
  int c4 = (idx & 31) * 4;
  float4 s = {0.f, 0.f, 0.f, 0.f};
  float d = 0.f;
#pragma unroll
  for (int z = 0; z < NZ; ++z) {
    float4 v = *(const float4*)(pnum + ((size_t)z * M_Q + q) * 128 + c4);
    s.x += v.x; s.y += v.y; s.z += v.z; s.w += v.w;
    d += pden[(size_t)z * M_Q + q];
  }
  float inv = 1.0f / d;
  int b = q / 49, p = q - b * 49;
  ushort4v o;
  o[0] = f2bf(s.x * inv); o[1] = f2bf(s.y * inv);
  o[2] = f2bf(s.z * inv); o[3] = f2bf(s.w * inv);
  *(ushort4v*)(fuse + (size_t)b * IN_ + p * 256 + 128 + c4) = o;
}

// ---------------- fc6: [512][12544] x W6p[2048][12544]^T bf16, K-split FZ=8 -----
// grid (32, 8) = 256 blocks; kz = bid%8 (XCD-local K-slice), nidx = rest.
__global__ __launch_bounds__(256) void fc6_kernel(
    const ushort* __restrict__ fuse, const ushort* __restrict__ W6p,
    float* __restrict__ part) {
  const int lane = threadIdx.x & 63, wv = threadIdx.x >> 6;
  const int r = lane & 15, g = lane >> 4;
  const int m0 = wv * 128;
  const int kz = blockIdx.x & 7;
  const int nidx = (blockIdx.x >> 3) + 4 * blockIdx.y;   // [0,32)
  const int n0 = nidx * 64;
  const int k0 = kz * 1568;
  f32x4 acc[8][4];
#pragma unroll
  for (int mt = 0; mt < 8; ++mt)
#pragma unroll
    for (int nt = 0; nt < 4; ++nt) acc[mt][nt] = f32x4{0.f, 0.f, 0.f, 0.f};
  const ushort* wrow[4];
#pragma unroll
  for (int nt = 0; nt < 4; ++nt)
    wrow[nt] = W6p + (size_t)(n0 + nt * 16 + r) * IN_;
  for (int kk = 0; kk < 1568; kk += 32) {
    const int kcol = k0 + kk + g * 8;
    short8 af[8];
#pragma unroll
    for (int mt = 0; mt < 8; ++mt)
      af[mt] = *(const short8*)(fuse + (size_t)(m0 + mt * 16 + r) * IN_ + kcol);
    short8 bfr[4];
#pragma unroll
    for (int nt = 0; nt < 4; ++nt) bfr[nt] = *(const short8*)(wrow[nt] + kcol);
#pragma unroll
    for (int mt = 0; mt < 8; ++mt)
#pragma unroll
      for (int nt = 0; nt < 4; ++nt) acc[mt][nt] = mfma16(af[mt], bfr[nt], acc[mt][nt]);
  }
#pragma unroll
  for (int mt = 0; mt < 8; ++mt)
#pragma unroll
    for (int nt = 0; nt < 4; ++nt)
#pragma unroll
      for (int e = 0; e < 4; ++e) {
        int m = m0 + mt * 16 + g * 4 + e;
        int n = n0 + nt * 16 + r;
        part[(size_t)kz * 1048576 + (size_t)m * 2048 + n] = acc[mt][nt][e];
      }
}

// sum split-K partials + bias + relu -> X7 bf16 [512][2048]
__global__ void fc6_reduce(const float* __restrict__ part, const float* __restrict__ b6c,
                           const float* __restrict__ b6r, ushort* __restrict__ X7) {
  int idx = blockIdx.x * 256 + threadIdx.x;  // exactly 512*2048
  int n = idx & 2047;
  float s = 0.f;
#pragma unroll
  for (int z = 0; z < FZ; ++z) s += part[(size_t)z * 1048576 + idx];
  s += (n < 1024) ? b6c[n] : b6r[n - 1024];
  s = fmaxf(s, 0.f);
  X7[idx] = f2bf(s);
}

// ---------------- fc7: [512][1024] x W7p[2048][1024]^T bf16 per half ------------
__global__ __launch_bounds__(128) void fc7_kernel(
    const ushort* __restrict__ X7, const ushort* __restrict__ W7p,
    const float* __restrict__ b7c, const float* __restrict__ b7r,
    float* __restrict__ out) {
  const int lane = threadIdx.x & 63, wv = threadIdx.x >> 6;
  const int r = lane & 15, g = lane >> 4;
  const int m0 = blockIdx.x * 32 + wv * 16;
  const int n0 = blockIdx.y * 64;
  const int half = (n0 >= 1024) ? 1 : 0;
  const int nn0 = n0 - half * 1024;
  const float* b7 = half ? b7r : b7c;
  f32x4 acc[4];
#pragma unroll
  for (int nt = 0; nt < 4; ++nt) acc[nt] = f32x4{0.f, 0.f, 0.f, 0.f};
  const ushort* arow = X7 + (size_t)(m0 + r) * 2048 + half * 1024;
  for (int kk = 0; kk < 1024; kk += 32) {
    short8 a = *(const short8*)(arow + kk + g * 8);
#pragma unroll
    for (int nt = 0; nt < 4; ++nt) {
      short8 bb = *(const short8*)(W7p + (size_t)(half * 1024 + nn0 + nt * 16 + r) * 1024 + kk + g * 8);
      acc[nt] = mfma16(a, bb, acc[nt]);
    }
  }
  float* obase = out + (size_t)half * 524288;
#pragma unroll
  for (int nt = 0; nt < 4; ++nt) {
#pragma unroll
    for (int e = 0; e < 4; ++e) {
      int m = m0 + g * 4 + e;
      int n = nn0 + nt * 16 + r;
      obase[(size_t)m * 1024 + n] = fmaxf(acc[nt][e] + b7[n], 0.f);
    }
  }
}

// ---------------- launch ----------------
extern "C" void kernel_launch(void* const* d_in, const int* in_sizes, int n_in,
                              void* d_out, int out_size, void* d_ws, size_t ws_size,
                              hipStream_t stream) {
  const float* x    = (const float*)d_in[0];
  const float* sup  = (const float*)d_in[1];
  const float* Wqv  = (const float*)d_in[2];
  const float* bqv  = (const float*)d_in[3];
  const float* Wqk  = (const float*)d_in[4];
  const float* bqk  = (const float*)d_in[5];
  const float* Wsv  = (const float*)d_in[6];
  const float* bsv  = (const float*)d_in[7];
  const float* Wsk  = (const float*)d_in[8];
  const float* bsk  = (const float*)d_in[9];
  const float* W6c  = (const float*)d_in[10];
  const float* b6c  = (const float*)d_in[11];
  const float* W7c  = (const float*)d_in[12];
  const float* b7c  = (const float*)d_in[13];
  const float* W6r  = (const float*)d_in[14];
  const float* b6r  = (const float*)d_in[15];
  const float* W7r  = (const float*)d_in[16];
  const float* b7r  = (const float*)d_in[17];
  float* out = (float*)d_out;

  char* base = (char*)d_ws;
  size_t off = 0;
  auto alloc = [&](size_t bytes) {
    char* p = base + off;
    off += (bytes + 255) & ~(size_t)255;
    return p;
  };
  // Region A: stage 1 = Xp/Xs hi/lo (28.9MB); stage 2 (after convs) = W6p+W7p (55.6MB)
  char* regionA = alloc((size_t)2048 * IN_ * 2 + (size_t)2048 * 1024 * 2);
  ushort* Xp_h = (ushort*)(regionA);
  ushort* Xp_l = (ushort*)(regionA + 12845056);
  ushort* Xs_h = (ushort*)(regionA + 25690112);
  ushort* Xs_l = (ushort*)(regionA + 27295744);
  ushort* W6p  = (ushort*)(regionA);
  ushort* W7p  = (ushort*)(regionA + (size_t)2048 * IN_ * 2);
  // Region B: attn pnum (51.4MB) then fc6 part (33.6MB)
  char* regionB = alloc((size_t)NZ * M_Q * 128 * 4);
  float* pnum = (float*)regionB;
  float* part = (float*)regionB;
  // Persistent region
  ushort* Wq_h = (ushort*)alloc(65536 * 2);
  ushort* Wq_l = (ushort*)alloc(65536 * 2);
  ushort* Ws_h = (ushort*)alloc(65536 * 2);
  ushort* Ws_l = (ushort*)alloc(65536 * 2);
  float*  biasq = (float*)alloc(256 * 4);
  float*  biass = (float*)alloc(256 * 4);
  ushort* fuse = (ushort*)alloc((size_t)512 * IN_ * 2);
  ushort* qk_h = (ushort*)alloc((size_t)M_Q * 128 * 2);
  ushort* sk_h = (ushort*)alloc((size_t)M_S * 128 * 2);
  ushort* svT  = (ushort*)alloc((size_t)M_S * 128 * 2);
  float*  pden = (float*)alloc((size_t)NZ * M_Q * 4);
  ushort* X7   = (ushort*)alloc((size_t)512 * 2048 * 2);
  if (off > ws_size) return;  // insufficient scratch; validation will show poison

  // 1) coalesced transpose+pack to bf16 hi/lo, token-major
  transpose_pack<<<dim3(512, 1, 4), dim3(256), 0, stream>>>(x, Xp_h, Xp_l, 49);
  transpose_pack<<<dim3(16, 4, 4), dim3(256), 0, stream>>>(sup, Xs_h, Xs_l, 196);
  pack_w<<<dim3(515), dim3(256), 0, stream>>>(Wqv, Wqk, bqv, bqk, Wsv, Wsk, bsv, bsk,
                                              Wq_h, Wq_l, biasq, Ws_h, Ws_l, biass);
  // 2) 1x1 convs with fused repack epilogues
  gemm_conv_q<<<dim3(392), dim3(256), 0, stream>>>(Xp_h, Xp_l, Wq_h, Wq_l, biasq,
                                                   fuse, qk_h);
  gemm_conv_s<<<dim3(49, 2), dim3(256), 0, stream>>>(Xs_h, Xs_l, Ws_h, Ws_l, biass,
                                                     svT, sk_h);
  // 3) pack MLP weights to bf16 into regionA (Xp/Xs now dead)
  pack_w6<<<dim3(2048), dim3(256), 0, stream>>>(W6c, W6r, W6p);
  pack_w7<<<dim3(8192), dim3(256), 0, stream>>>(W7c, W7r, W7p);
  // 4) fused attention (dbuf LDS, 16 q/wave, key-split) + combine
  attn_kernel<<<dim3(392, NZ), dim3(256), 0, stream>>>(qk_h, sk_h, svT, pnum, pden);
  attn_reduce<<<dim3(3136), dim3(256), 0, stream>>>(pnum, pden, fuse);
  // 5) fc6 (K-split, XCD-local kz) + reduce+relu
  fc6_kernel<<<dim3(32, FZ), dim3(256), 0, stream>>>(fuse, W6p, part);
  fc6_reduce<<<dim3(4096), dim3(256), 0, stream>>>(part, b6c, b6r, X7);
  // 6) fc7 + bias + relu -> d_out (xc then xr)
  fc7_kernel<<<dim3(16, 32), dim3(128), 0, stream>>>(X7, W7p, b7c, b7r, out);
}

// Round 11
// 325.056 us; speedup vs baseline: 1.0139x; 1.0139x over previous
//
#include <hip/hip_runtime.h>
#include <hip/hip_bf16.h>
#include <stdint.h>

typedef short short8 __attribute__((ext_vector_type(8)));
typedef float f32x4 __attribute__((ext_vector_type(4)));
typedef ushort ushort4v __attribute__((ext_vector_type(4)));

#define M_Q   25088   // B*H*W = 512*49
#define M_S   3136    // NS*HS*WS = 16*196
#define IN_   12544
#define LOG2E  1.44269504f
#define SHIFT2 57.7078016f   // 40 * log2(e); exp(l-40) == exp2(l*log2e - SHIFT2)
#define NZ    4       // attention key-split
#define FZ    8       // fc6 K-split
#define KSTR  136     // K-LDS row stride (ushorts): 272B = 4-bank shift per row
#define PSTR  40      // P-LDS row stride (ushorts): >=32 (row length!) + pad
#define WSTR  40      // fc6 W-LDS row stride (ushorts): 80B = 20-bank shift per row

__device__ __forceinline__ ushort f2bf(float f) {
  union { float f; uint32_t u; } v; v.f = f;
  uint32_t r = v.u + 0x7fffu + ((v.u >> 16) & 1u);
  return (ushort)(r >> 16);
}
// cheap round-half-up; used only for P (positive values)
__device__ __forceinline__ ushort f2bf_fast(float f) {
  union { float f; uint32_t u; } v; v.f = f;
  return (ushort)((v.u + 0x8000u) >> 16);
}
__device__ __forceinline__ float bf2f(ushort u) {
  union { uint32_t u; float f; } v; v.u = ((uint32_t)u) << 16;
  return v.f;
}
__device__ __forceinline__ f32x4 mfma16(short8 a, short8 b, f32x4 c) {
  return __builtin_amdgcn_mfma_f32_16x16x32_bf16(a, b, c, 0, 0, 0);
}

// ---------------- coalesced transpose+pack: [B][256][P] f32 -> [B*P][256] hi/lo bf16
__global__ __launch_bounds__(256) void transpose_pack(
    const float* __restrict__ src, ushort* __restrict__ hi,
    ushort* __restrict__ lo, int P) {
  const int b = blockIdx.x;
  const int p0 = blockIdx.y * 49;
  const int w = threadIdx.x >> 6, l = threadIdx.x & 63;
  if (l >= 49) return;
  const int p = p0 + l;
  const float* sb = src + (size_t)b * 256 * P + p;
  const size_t orow = ((size_t)b * P + p) * 256;
  const int ch0 = blockIdx.z * 2;
#pragma unroll
  for (int ch = 0; ch < 2; ++ch) {
    const int c0 = ((ch0 + ch) * 4 + w) * 8;
    short8 h8, l8;
#pragma unroll
    for (int j = 0; j < 8; ++j) {
      float v = sb[(size_t)(c0 + j) * P];
      ushort h = f2bf(v);
      h8[j] = (short)h;
      l8[j] = (short)f2bf(v - bf2f(h));
    }
    *(short8*)(hi + orow + c0) = h8;
    *(short8*)(lo + orow + c0) = l8;
  }
}

// stack conv weights [128,256]+[128,256] -> [256,256] hi/lo, plus biases
__global__ void pack_w(const float* __restrict__ Wqv, const float* __restrict__ Wqk,
                       const float* __restrict__ bqv, const float* __restrict__ bqk,
                       const float* __restrict__ Wsv, const float* __restrict__ Wsk,
                       const float* __restrict__ bsv, const float* __restrict__ bsk,
                       ushort* __restrict__ Wq_h, ushort* __restrict__ Wq_l, float* __restrict__ biasq,
                       ushort* __restrict__ Ws_h, ushort* __restrict__ Ws_l, float* __restrict__ biass) {
  int idx = blockIdx.x * 256 + threadIdx.x;
  if (idx < 65536) {
    int n = idx >> 8;
    const float* W = (n < 128) ? (Wqv + n * 256) : (Wqk + (n - 128) * 256);
    float v = W[idx & 255];
    ushort h = f2bf(v);
    Wq_h[idx] = h; Wq_l[idx] = f2bf(v - bf2f(h));
  } else if (idx < 131072) {
    int j = idx - 65536;
    int n = j >> 8;
    const float* W = (n < 128) ? (Wsv + n * 256) : (Wsk + (n - 128) * 256);
    float v = W[j & 255];
    ushort h = f2bf(v);
    Ws_h[j] = h; Ws_l[j] = f2bf(v - bf2f(h));
  } else if (idx < 131328) {
    int n = idx - 131072;
    biasq[n] = (n < 128) ? bqv[n] : bqk[n - 128];
  } else if (idx < 131584) {
    int n = idx - 131328;
    biass[n] = (n < 128) ? bsv[n] : bsk[n - 128];
  }
}

// W6 [n][c*49+p] f32 -> W6p [n][p*256+c] bf16 via LDS tile (both sides coalesced)
__global__ __launch_bounds__(256) void pack_w6(
    const float* __restrict__ W6c, const float* __restrict__ W6r,
    ushort* __restrict__ W6p) {
  __shared__ ushort tile[IN_];
  const int n = blockIdx.x;
  const float* src = (n < 1024) ? (W6c + (size_t)n * IN_)
                                : (W6r + (size_t)(n - 1024) * IN_);
  ushort* dst = W6p + (size_t)n * IN_;
#pragma unroll 7
  for (int j = 0; j < 49; ++j) {
    int i = j * 256 + threadIdx.x;
    tile[i] = f2bf(src[i]);
  }
  __syncthreads();
#pragma unroll 7
  for (int j = 0; j < 49; ++j) {
    int o = j * 256 + threadIdx.x;
    int c = o & 255, p = o >> 8;
    dst[o] = tile[c * 49 + p];
  }
}

// W7 -> bf16 [2048][1024] (xc rows then xr rows)
__global__ void pack_w7(const float* __restrict__ W7c, const float* __restrict__ W7r,
                        ushort* __restrict__ W7p) {
  int idx = blockIdx.x * 256 + threadIdx.x;  // exactly 2048*1024
  float v = (idx < 1048576) ? W7c[idx] : W7r[idx - 1048576];
  W7p[idx] = f2bf(v);
}

// ---------------- conv GEMM Q (unsplit, acc[16]) ------------------------------
// qv half (n<128): 2-term split-bf16 -> fuse token-major.
// qk half (n>=128): 3-term (f32-accurate) -> qk_h bf16 scaled by log2(e).
__global__ __launch_bounds__(256) void gemm_conv_q(
    const ushort* __restrict__ Ah, const ushort* __restrict__ Al,
    const ushort* __restrict__ Bh, const ushort* __restrict__ Bl,
    const float* __restrict__ bias, ushort* __restrict__ fuse,
    ushort* __restrict__ qk_h) {
  const int lane = threadIdx.x & 63, wv = threadIdx.x >> 6;
  const int r = lane & 15, g = lane >> 4;
  const int row0 = blockIdx.x * 64 + wv * 16;
  const ushort* arh = Ah + (size_t)(row0 + r) * 256 + g * 8;
  const ushort* arl = Al + (size_t)(row0 + r) * 256 + g * 8;
  f32x4 acc[16];
#pragma unroll
  for (int i = 0; i < 16; ++i) acc[i] = f32x4{0.f, 0.f, 0.f, 0.f};
#pragma unroll
  for (int kc = 0; kc < 8; ++kc) {
    short8 ah = *(const short8*)(arh + kc * 32);
    short8 al = *(const short8*)(arl + kc * 32);
    const ushort* bbh = Bh + r * 256 + kc * 32 + g * 8;
    const ushort* bbl = Bl + r * 256 + kc * 32 + g * 8;
#pragma unroll
    for (int nt = 0; nt < 16; ++nt) {
      short8 bh = *(const short8*)(bbh + nt * 16 * 256);
      acc[nt] = mfma16(ah, bh, acc[nt]);
      acc[nt] = mfma16(al, bh, acc[nt]);
      if (nt >= 8) {  // qk half needs full accuracy: + ah*bl
        short8 bl = *(const short8*)(bbl + nt * 16 * 256);
        acc[nt] = mfma16(ah, bl, acc[nt]);
      }
    }
  }
  const int qr = row0 + g * 4;
#pragma unroll
  for (int nt = 0; nt < 16; ++nt) {
    int n = nt * 16 + r;
    float bs = bias[n];
#pragma unroll
    for (int e = 0; e < 4; ++e) {
      float v = acc[nt][e] + bs;
      int q = qr + e;
      if (nt < 8) {
        int b = q / 49, p = q - b * 49;
        fuse[(size_t)b * IN_ + p * 256 + n] = f2bf(v);
      } else {
        qk_h[(size_t)q * 128 + (n - 128)] = f2bf(v * LOG2E);
      }
    }
  }
}

// S variant (n-split x2): nb==0 -> svT (2-term); nb==1 -> sk_h (3-term, f32-acc)
__global__ __launch_bounds__(256) void gemm_conv_s(
    const ushort* __restrict__ Ah, const ushort* __restrict__ Al,
    const ushort* __restrict__ Bh, const ushort* __restrict__ Bl,
    const float* __restrict__ bias, ushort* __restrict__ svT,
    ushort* __restrict__ sk_h) {
  const int lane = threadIdx.x & 63, wv = threadIdx.x >> 6;
  const int r = lane & 15, g = lane >> 4;
  const int row0 = blockIdx.x * 64 + wv * 16;
  const int nb = blockIdx.y;
  const ushort* arh = Ah + (size_t)(row0 + r) * 256 + g * 8;
  const ushort* arl = Al + (size_t)(row0 + r) * 256 + g * 8;
  f32x4 acc[8];
#pragma unroll
  for (int i = 0; i < 8; ++i) acc[i] = f32x4{0.f, 0.f, 0.f, 0.f};
#pragma unroll
  for (int kc = 0; kc < 8; ++kc) {
    short8 ah = *(const short8*)(arh + kc * 32);
    short8 al = *(const short8*)(arl + kc * 32);
    const ushort* bbh = Bh + (size_t)(nb * 128 + r) * 256 + kc * 32 + g * 8;
    const ushort* bbl = Bl + (size_t)(nb * 128 + r) * 256 + kc * 32 + g * 8;
#pragma unroll
    for (int nt = 0; nt < 8; ++nt) {
      short8 bh = *(const short8*)(bbh + nt * 16 * 256);
      acc[nt] = mfma16(ah, bh, acc[nt]);
      acc[nt] = mfma16(al, bh, acc[nt]);
      if (nb == 1) {
        short8 bl = *(const short8*)(bbl + nt * 16 * 256);
        acc[nt] = mfma16(ah, bl, acc[nt]);
      }
    }
  }
  const int qr = row0 + g * 4;
#pragma unroll
  for (int nt = 0; nt < 8; ++nt) {
    int nl = nt * 16 + r;
    float bs = bias[nb * 128 + nl];
#pragma unroll
    for (int e = 0; e < 4; ++e) {
      float v = acc[nt][e] + bs;
      int k = qr + e;
      if (nb == 0) {
        svT[(size_t)nl * M_S + k] = f2bf(v);
      } else {
        sk_h[(size_t)k * 128 + nl] = f2bf(v);
      }
    }
  }
}

// ---------------- fused attention: dbuf LDS, 32 q-rows/wave (R9 geometry) -----
// block = 256 thr = 4 waves; 128 q-rows/block; key chunk z of NZ.
// Q pre-scaled by log2(e); P = exp2(logit2 - SHIFT2) -> single v_exp_f32.
#define LOAD_TILE(T)                                                            \
  do {                                                                          \
    const int kb_ = (T) * 32;                                                   \
    pkh0 = *(const short8*)(Kh + (size_t)(kb_ + row0s) * 128 + c8s * 8);        \
    pkh1 = *(const short8*)(Kh + (size_t)(kb_ + row0s + 16) * 128 + c8s * 8);   \
    pv0  = *(const short8*)(Vt + (size_t)cvs * M_S + kb_ + kc2s * 8);           \
    pv1  = *(const short8*)(Vt + (size_t)(cvs + 64) * M_S + kb_ + kc2s * 8);    \
  } while (0)
#define PUBLISH(B)                                                              \
  do {                                                                          \
    *(short8*)(&khs[B][kloff0]) = pkh0;                                         \
    *(short8*)(&khs[B][kloff1]) = pkh1;                                         \
    *(short8*)(&vvs[B][voff0]) = pv0;                                           \
    *(short8*)(&vvs[B][voff1]) = pv1;                                           \
  } while (0)

__global__ __launch_bounds__(256) void attn_kernel(
    const ushort* __restrict__ Qh, const ushort* __restrict__ Kh,
    const ushort* __restrict__ Vt, float* __restrict__ pnum,
    float* __restrict__ pden) {
  __shared__ ushort khs[2][32 * KSTR];
  __shared__ ushort vvs[2][128 * 32];
  __shared__ ushort plds[4][16 * PSTR];
  const int tid = threadIdx.x;
  const int w = tid >> 6, lane = tid & 63;
  const int r = lane & 15, g = lane >> 4;
  const int q0 = blockIdx.x * 128 + w * 32;
  const int z = blockIdx.y;
  const int t0 = z * 24 + (z < 2 ? z : 2);
  const int tn = 24 + (z < 2 ? 1 : 0);
  ushort* pw = plds[w];

  const int row0s = tid >> 4, c8s = tid & 15;
  const int cvs = tid >> 2, kc2s = tid & 3;
  const int kloff0 = row0s * KSTR + c8s * 8;
  const int kloff1 = (row0s + 16) * KSTR + c8s * 8;
  const int voff0 = cvs * 32 + kc2s * 8;
  const int voff1 = (cvs + 64) * 32 + kc2s * 8;

  short8 aq[2][4];
#pragma unroll
  for (int mt = 0; mt < 2; ++mt)
#pragma unroll
    for (int kc = 0; kc < 4; ++kc)
      aq[mt][kc] = *(const short8*)(Qh + (size_t)(q0 + mt * 16 + r) * 128 + kc * 32 + g * 8);

  f32x4 acc[2][8];
#pragma unroll
  for (int mt = 0; mt < 2; ++mt)
#pragma unroll
    for (int ct = 0; ct < 8; ++ct) acc[mt][ct] = f32x4{0.f, 0.f, 0.f, 0.f};
  float den[2][4];
#pragma unroll
  for (int mt = 0; mt < 2; ++mt)
#pragma unroll
    for (int e = 0; e < 4; ++e) den[mt][e] = 0.f;

  short8 pkh0, pkh1, pv0, pv1;
  LOAD_TILE(t0);
  PUBLISH(0);
  if (tn > 1) LOAD_TILE(t0 + 1);
  __syncthreads();

  for (int i = 0; i < tn; ++i) {
    const int b = i & 1;
    if (i + 1 < tn) {
      PUBLISH(b ^ 1);                 // buf^1 last read at barrier ending i-1
      if (i + 2 < tn) LOAD_TILE(t0 + i + 2);
    }
    // ---- QK^T from LDS buf b (bf16 x bf16) ----
    f32x4 lg[2][2];
#pragma unroll
    for (int kt = 0; kt < 2; ++kt) {
      const int kbase = (kt * 16 + r) * KSTR;
      short8 bh[4];
#pragma unroll
      for (int kc = 0; kc < 4; ++kc)
        bh[kc] = *(const short8*)(&khs[b][kbase + (kc * 4 + g) * 8]);
#pragma unroll
      for (int mt = 0; mt < 2; ++mt) {
        f32x4 c = f32x4{0.f, 0.f, 0.f, 0.f};
#pragma unroll
        for (int kc = 0; kc < 4; ++kc)
          c = mfma16(aq[mt][kc], bh[kc], c);
        lg[mt][kt] = c;
      }
    }
    // ---- V fragments (mt-invariant) ----
    short8 vf[8];
#pragma unroll
    for (int ct = 0; ct < 8; ++ct)
      vf[ct] = *(const short8*)(&vvs[b][(ct * 16 + r) * 32 + g * 8]);
    // ---- per-mt: exp2 -> P (per-wave LDS slice) -> PV ----
#pragma unroll
    for (int mt = 0; mt < 2; ++mt) {
#pragma unroll
      for (int kt = 0; kt < 2; ++kt)
#pragma unroll
        for (int e = 0; e < 4; ++e) {
          float p = __builtin_amdgcn_exp2f(lg[mt][kt][e] - SHIFT2);
          den[mt][e] += p;
          pw[(g * 4 + e) * PSTR + kt * 16 + r] = f2bf_fast(p);
        }
      short8 pf = *(const short8*)(pw + r * PSTR + g * 8);
#pragma unroll
      for (int ct = 0; ct < 8; ++ct)
        acc[mt][ct] = mfma16(pf, vf[ct], acc[mt][ct]);
    }
    __syncthreads();
  }

#pragma unroll
  for (int mt = 0; mt < 2; ++mt)
#pragma unroll
    for (int e = 0; e < 4; ++e) {
      float d = den[mt][e];
      d += __shfl_xor(d, 1);
      d += __shfl_xor(d, 2);
      d += __shfl_xor(d, 4);
      d += __shfl_xor(d, 8);
      den[mt][e] = d;
    }
#pragma unroll
  for (int mt = 0; mt < 2; ++mt)
#pragma unroll
    for (int ct = 0; ct < 8; ++ct)
#pragma unroll
      for (int e = 0; e < 4; ++e) {
        int q = q0 + mt * 16 + g * 4 + e;
        int c = ct * 16 + r;
        pnum[((size_t)z * M_Q + q) * 128 + c] = acc[mt][ct][e];
      }
  if (r == 0) {
#pragma unroll
    for (int mt = 0; mt < 2; ++mt)
#pragma unroll
      for (int e = 0; e < 4; ++e)
        pden[(size_t)z * M_Q + q0 + mt * 16 + g * 4 + e] = den[mt][e];
  }
}

// combine key-split partials -> att half of fuse (token-major, coalesced)
__global__ void attn_reduce(const float* __restrict__ pnum, const float* __restrict__ pden,
                            ushort* __restrict__ fuse) {
  int idx = blockIdx.x * 256 + threadIdx.x;  // exactly 25088*32 (c-quads)
  int q = idx >> 5;
  int c4 = (idx & 31) * 4;
  float4 s = {0.f, 0.f, 0.f, 0.f};
  float d = 0.f;
#pragma unroll
  for (int z = 0; z < NZ; ++z) {
    float4 v = *(const float4*)(pnum + ((size_t)z * M_Q + q) * 128 + c4);
    s.x += v.x; s.y += v.y; s.z += v.z; s.w += v.w;
    d += pden[(size_t)z * M_Q + q];
  }
  float inv = 1.0f / d;
  int b = q / 49, p = q - b * 49;
  ushort4v o;
  o[0] = f2bf(s.x * inv); o[1] = f2bf(s.y * inv);
  o[2] = f2bf(s.z * inv); o[3] = f2bf(s.w * inv);
  *(ushort4v*)(fuse + (size_t)b * IN_ + p * 256 + 128 + c4) = o;
}

// ---------------- fc6: [512][12544] x W6p[2048][12544]^T bf16, K-split FZ=8 -----
// grid (32, 8) = 256 blocks; kz = bid&7 (XCD-local K-slice), nidx = rest.
// NEW: W6p (HBM-streaming operand) staged via double-buffered LDS with depth-2
// register prefetch; fuse (L2-resident slice) stays global-direct.
__global__ __launch_bounds__(256) void fc6_kernel(
    const ushort* __restrict__ fuse, const ushort* __restrict__ W6p,
    float* __restrict__ part) {
  __shared__ ushort wlds[2][64 * WSTR];
  const int lane = threadIdx.x & 63, wv = threadIdx.x >> 6;
  const int r = lane & 15, g = lane >> 4;
  const int m0 = wv * 128;
  const int kz = blockIdx.x & 7;
  const int nidx = (blockIdx.x >> 3) + 4 * blockIdx.y;   // [0,32)
  const int n0 = nidx * 64;
  const int k0 = kz * 1568;

  // staging geometry: 64 rows x 32 k = 4KB/slab; thread t stages one short8.
  const int srow = threadIdx.x >> 2;          // 0..63
  const int skc  = (threadIdx.x & 3) * 8;     // 0,8,16,24
  const size_t wgbase = (size_t)(n0 + srow) * IN_ + k0 + skc;
  const int wloff = srow * WSTR + skc;

  f32x4 acc[8][4];
#pragma unroll
  for (int mt = 0; mt < 8; ++mt)
#pragma unroll
    for (int nt = 0; nt < 4; ++nt) acc[mt][nt] = f32x4{0.f, 0.f, 0.f, 0.f};

  short8 rA, rB;
  rA = *(const short8*)(W6p + wgbase);                 // slab 0
  *(short8*)(&wlds[0][wloff]) = rA;
  rA = *(const short8*)(W6p + wgbase + 32);            // slab 1
  rB = *(const short8*)(W6p + wgbase + 64);            // slab 2
  __syncthreads();

  for (int t = 0; t < 49; ++t) {
    const int b = t & 1;
    if (t + 1 < 49) {
      *(short8*)(&wlds[b ^ 1][wloff]) = rA;            // publish slab t+1
      rA = rB;
      if (t + 3 < 49) rB = *(const short8*)(W6p + wgbase + (size_t)(t + 3) * 32);
    }
    const int kcol = k0 + t * 32 + g * 8;
    short8 af[8];
#pragma unroll
    for (int mt = 0; mt < 8; ++mt)
      af[mt] = *(const short8*)(fuse + (size_t)(m0 + mt * 16 + r) * IN_ + kcol);
    short8 bfr[4];
#pragma unroll
    for (int nt = 0; nt < 4; ++nt)
      bfr[nt] = *(const short8*)(&wlds[b][(nt * 16 + r) * WSTR + g * 8]);
#pragma unroll
    for (int mt = 0; mt < 8; ++mt)
#pragma unroll
      for (int nt = 0; nt < 4; ++nt) acc[mt][nt] = mfma16(af[mt], bfr[nt], acc[mt][nt]);
    __syncthreads();
  }
#pragma unroll
  for (int mt = 0; mt < 8; ++mt)
#pragma unroll
    for (int nt = 0; nt < 4; ++nt)
#pragma unroll
      for (int e = 0; e < 4; ++e) {
        int m = m0 + mt * 16 + g * 4 + e;
        int n = n0 + nt * 16 + r;
        part[(size_t)kz * 1048576 + (size_t)m * 2048 + n] = acc[mt][nt][e];
      }
}

// sum split-K partials + bias + relu -> X7 bf16 [512][2048]
__global__ void fc6_reduce(const float* __restrict__ part, const float* __restrict__ b6c,
                           const float* __restrict__ b6r, ushort* __restrict__ X7) {
  int idx = blockIdx.x * 256 + threadIdx.x;  // exactly 512*2048
  int n = idx & 2047;
  float s = 0.f;
#pragma unroll
  for (int z = 0; z < FZ; ++z) s += part[(size_t)z * 1048576 + idx];
  s += (n < 1024) ? b6c[n] : b6r[n - 1024];
  s = fmaxf(s, 0.f);
  X7[idx] = f2bf(s);
}

// ---------------- fc7: [512][1024] x W7p[2048][1024]^T bf16 per half ------------
__global__ __launch_bounds__(128) void fc7_kernel(
    const ushort* __restrict__ X7, const ushort* __restrict__ W7p,
    const float* __restrict__ b7c, const float* __restrict__ b7r,
    float* __restrict__ out) {
  const int lane = threadIdx.x & 63, wv = threadIdx.x >> 6;
  const int r = lane & 15, g = lane >> 4;
  const int m0 = blockIdx.x * 32 + wv * 16;
  const int n0 = blockIdx.y * 64;
  const int half = (n0 >= 1024) ? 1 : 0;
  const int nn0 = n0 - half * 1024;
  const float* b7 = half ? b7r : b7c;
  f32x4 acc[4];
#pragma unroll
  for (int nt = 0; nt < 4; ++nt) acc[nt] = f32x4{0.f, 0.f, 0.f, 0.f};
  const ushort* arow = X7 + (size_t)(m0 + r) * 2048 + half * 1024;
  for (int kk = 0; kk < 1024; kk += 32) {
    short8 a = *(const short8*)(arow + kk + g * 8);
#pragma unroll
    for (int nt = 0; nt < 4; ++nt) {
      short8 bb = *(const short8*)(W7p + (size_t)(half * 1024 + nn0 + nt * 16 + r) * 1024 + kk + g * 8);
      acc[nt] = mfma16(a, bb, acc[nt]);
    }
  }
  float* obase = out + (size_t)half * 524288;
#pragma unroll
  for (int nt = 0; nt < 4; ++nt) {
#pragma unroll
    for (int e = 0; e < 4; ++e) {
      int m = m0 + g * 4 + e;
      int n = nn0 + nt * 16 + r;
      obase[(size_t)m * 1024 + n] = fmaxf(acc[nt][e] + b7[n], 0.f);
    }
  }
}

// ---------------- launch ----------------
extern "C" void kernel_launch(void* const* d_in, const int* in_sizes, int n_in,
                              void* d_out, int out_size, void* d_ws, size_t ws_size,
                              hipStream_t stream) {
  const float* x    = (const float*)d_in[0];
  const float* sup  = (const float*)d_in[1];
  const float* Wqv  = (const float*)d_in[2];
  const float* bqv  = (const float*)d_in[3];
  const float* Wqk  = (const float*)d_in[4];
  const float* bqk  = (const float*)d_in[5];
  const float* Wsv  = (const float*)d_in[6];
  const float* bsv  = (const float*)d_in[7];
  const float* Wsk  = (const float*)d_in[8];
  const float* bsk  = (const float*)d_in[9];
  const float* W6c  = (const float*)d_in[10];
  const float* b6c  = (const float*)d_in[11];
  const float* W7c  = (const float*)d_in[12];
  const float* b7c  = (const float*)d_in[13];
  const float* W6r  = (const float*)d_in[14];
  const float* b6r  = (const float*)d_in[15];
  const float* W7r  = (const float*)d_in[16];
  const float* b7r  = (const float*)d_in[17];
  float* out = (float*)d_out;

  char* base = (char*)d_ws;
  size_t off = 0;
  auto alloc = [&](size_t bytes) {
    char* p = base + off;
    off += (bytes + 255) & ~(size_t)255;
    return p;
  };
  // Region A: stage 1 = Xp/Xs hi/lo (28.9MB); stage 2 (after convs) = W6p+W7p (55.6MB)
  char* regionA = alloc((size_t)2048 * IN_ * 2 + (size_t)2048 * 1024 * 2);
  ushort* Xp_h = (ushort*)(regionA);
  ushort* Xp_l = (ushort*)(regionA + 12845056);
  ushort* Xs_h = (ushort*)(regionA + 25690112);
  ushort* Xs_l = (ushort*)(regionA + 27295744);
  ushort* W6p  = (ushort*)(regionA);
  ushort* W7p  = (ushort*)(regionA + (size_t)2048 * IN_ * 2);
  // Region B: attn pnum (51.4MB) then fc6 part (33.6MB)
  char* regionB = alloc((size_t)NZ * M_Q * 128 * 4);
  float* pnum = (float*)regionB;
  float* part = (float*)regionB;
  // Persistent region
  ushort* Wq_h = (ushort*)alloc(65536 * 2);
  ushort* Wq_l = (ushort*)alloc(65536 * 2);
  ushort* Ws_h = (ushort*)alloc(65536 * 2);
  ushort* Ws_l = (ushort*)alloc(65536 * 2);
  float*  biasq = (float*)alloc(256 * 4);
  float*  biass = (float*)alloc(256 * 4);
  ushort* fuse = (ushort*)alloc((size_t)512 * IN_ * 2);
  ushort* qk_h = (ushort*)alloc((size_t)M_Q * 128 * 2);
  ushort* sk_h = (ushort*)alloc((size_t)M_S * 128 * 2);
  ushort* svT  = (ushort*)alloc((size_t)M_S * 128 * 2);
  float*  pden = (float*)alloc((size_t)NZ * M_Q * 4);
  ushort* X7   = (ushort*)alloc((size_t)512 * 2048 * 2);
  if (off > ws_size) return;  // insufficient scratch; validation will show poison

  // 1) coalesced transpose+pack to bf16 hi/lo, token-major
  transpose_pack<<<dim3(512, 1, 4), dim3(256), 0, stream>>>(x, Xp_h, Xp_l, 49);
  transpose_pack<<<dim3(16, 4, 4), dim3(256), 0, stream>>>(sup, Xs_h, Xs_l, 196);
  pack_w<<<dim3(515), dim3(256), 0, stream>>>(Wqv, Wqk, bqv, bqk, Wsv, Wsk, bsv, bsk,
                                              Wq_h, Wq_l, biasq, Ws_h, Ws_l, biass);
  // 2) 1x1 convs with fused repack epilogues
  gemm_conv_q<<<dim3(392), dim3(256), 0, stream>>>(Xp_h, Xp_l, Wq_h, Wq_l, biasq,
                                                   fuse, qk_h);
  gemm_conv_s<<<dim3(49, 2), dim3(256), 0, stream>>>(Xs_h, Xs_l, Ws_h, Ws_l, biass,
                                                     svT, sk_h);
  // 3) pack MLP weights to bf16 into regionA (Xp/Xs now dead)
  pack_w6<<<dim3(2048), dim3(256), 0, stream>>>(W6c, W6r, W6p);
  pack_w7<<<dim3(8192), dim3(256), 0, stream>>>(W7c, W7r, W7p);
  // 4) fused attention (dbuf LDS, 32 q/wave, key-split) + combine
  attn_kernel<<<dim3(196, NZ), dim3(256), 0, stream>>>(qk_h, sk_h, svT, pnum, pden);
  attn_reduce<<<dim3(3136), dim3(256), 0, stream>>>(pnum, pden, fuse);
  // 5) fc6 (K-split, XCD-local kz, W6p LDS-staged) + reduce+relu
  fc6_kernel<<<dim3(32, FZ), dim3(256), 0, stream>>>(fuse, W6p, part);
  fc6_reduce<<<dim3(4096), dim3(256), 0, stream>>>(part, b6c, b6r, X7);
  // 6) fc7 + bias + relu -> d_out (xc then xr)
  fc7_kernel<<<dim3(16, 32), dim3(128), 0, stream>>>(X7, W7p, b7c, b7r, out);
}

// Round 12
// 287.913 us; speedup vs baseline: 1.1447x; 1.1290x over previous
//
#include <hip/hip_runtime.h>
#include <hip/hip_bf16.h>
#include <stdint.h>

typedef short short8 __attribute__((ext_vector_type(8)));
typedef float f32x4 __attribute__((ext_vector_type(4)));
typedef ushort ushort4v __attribute__((ext_vector_type(4)));

#define M_Q   25088   // B*H*W = 512*49
#define M_S   3136    // NS*HS*WS = 16*196
#define IN_   12544
#define LOG2E  1.44269504f
#define SHIFT2 57.7078016f   // 40 * log2(e); exp(l-40) == exp2(l*log2e - SHIFT2)
#define NZ    4       // attention key-split
#define FZ    8       // fc6 K-split
#define KSTR  136     // K-LDS row stride (ushorts): 272B = 4-bank shift per row
#define PSTR  40      // P-LDS row stride (ushorts): >=32 (row length!) + pad
#define WSTR  40      // fc6 W-LDS row stride (ushorts)

__device__ __forceinline__ ushort f2bf(float f) {
  union { float f; uint32_t u; } v; v.f = f;
  uint32_t r = v.u + 0x7fffu + ((v.u >> 16) & 1u);
  return (ushort)(r >> 16);
}
// cheap round-half-up; used only for P (positive values)
__device__ __forceinline__ ushort f2bf_fast(float f) {
  union { float f; uint32_t u; } v; v.f = f;
  return (ushort)((v.u + 0x8000u) >> 16);
}
__device__ __forceinline__ float bf2f(ushort u) {
  union { uint32_t u; float f; } v; v.u = ((uint32_t)u) << 16;
  return v.f;
}
__device__ __forceinline__ f32x4 mfma16(short8 a, short8 b, f32x4 c) {
  return __builtin_amdgcn_mfma_f32_16x16x32_bf16(a, b, c, 0, 0, 0);
}

// ---------------- coalesced transpose+pack: [B][256][P] f32 -> [B*P][256] bf16
__global__ __launch_bounds__(256) void transpose_pack(
    const float* __restrict__ src, ushort* __restrict__ hi, int P) {
  const int b = blockIdx.x;
  const int p0 = blockIdx.y * 49;
  const int w = threadIdx.x >> 6, l = threadIdx.x & 63;
  if (l >= 49) return;
  const int p = p0 + l;
  const float* sb = src + (size_t)b * 256 * P + p;
  const size_t orow = ((size_t)b * P + p) * 256;
  const int ch0 = blockIdx.z * 2;
#pragma unroll
  for (int ch = 0; ch < 2; ++ch) {
    const int c0 = ((ch0 + ch) * 4 + w) * 8;
    short8 h8;
#pragma unroll
    for (int j = 0; j < 8; ++j) h8[j] = (short)f2bf(sb[(size_t)(c0 + j) * P]);
    *(short8*)(hi + orow + c0) = h8;
  }
}

// stack conv weights [128,256]+[128,256] -> [256,256] bf16, plus biases
__global__ void pack_w(const float* __restrict__ Wqv, const float* __restrict__ Wqk,
                       const float* __restrict__ bqv, const float* __restrict__ bqk,
                       const float* __restrict__ Wsv, const float* __restrict__ Wsk,
                       const float* __restrict__ bsv, const float* __restrict__ bsk,
                       ushort* __restrict__ Wq_h, float* __restrict__ biasq,
                       ushort* __restrict__ Ws_h, float* __restrict__ biass) {
  int idx = blockIdx.x * 256 + threadIdx.x;
  if (idx < 65536) {
    int n = idx >> 8;
    const float* W = (n < 128) ? (Wqv + n * 256) : (Wqk + (n - 128) * 256);
    Wq_h[idx] = f2bf(W[idx & 255]);
  } else if (idx < 131072) {
    int j = idx - 65536;
    int n = j >> 8;
    const float* W = (n < 128) ? (Wsv + n * 256) : (Wsk + (n - 128) * 256);
    Ws_h[j] = f2bf(W[j & 255]);
  } else if (idx < 131328) {
    int n = idx - 131072;
    biasq[n] = (n < 128) ? bqv[n] : bqk[n - 128];
  } else if (idx < 131584) {
    int n = idx - 131328;
    biass[n] = (n < 128) ? bsv[n] : bsk[n - 128];
  }
}

// W6 [n][c*49+p] f32 -> W6p [n][p*256+c] bf16 via LDS tile (both sides coalesced)
__global__ __launch_bounds__(256) void pack_w6(
    const float* __restrict__ W6c, const float* __restrict__ W6r,
    ushort* __restrict__ W6p) {
  __shared__ ushort tile[IN_];
  const int n = blockIdx.x;
  const float* src = (n < 1024) ? (W6c + (size_t)n * IN_)
                                : (W6r + (size_t)(n - 1024) * IN_);
  ushort* dst = W6p + (size_t)n * IN_;
#pragma unroll 7
  for (int j = 0; j < 49; ++j) {
    int i = j * 256 + threadIdx.x;
    tile[i] = f2bf(src[i]);
  }
  __syncthreads();
#pragma unroll 7
  for (int j = 0; j < 49; ++j) {
    int o = j * 256 + threadIdx.x;
    int c = o & 255, p = o >> 8;
    dst[o] = tile[c * 49 + p];
  }
}

// W7 -> bf16 [2048][1024] (xc rows then xr rows)
__global__ void pack_w7(const float* __restrict__ W7c, const float* __restrict__ W7r,
                        ushort* __restrict__ W7p) {
  int idx = blockIdx.x * 256 + threadIdx.x;  // exactly 2048*1024
  float v = (idx < 1048576) ? W7c[idx] : W7r[idx - 1048576];
  W7p[idx] = f2bf(v);
}

// ---------------- conv GEMM Q (plain bf16, acc[16]) ----------------------------
// qv half (n<128) -> fuse token-major; qk half (n>=128) -> qk_h scaled by log2(e)
__global__ __launch_bounds__(256) void gemm_conv_q(
    const ushort* __restrict__ Ah, const ushort* __restrict__ Bh,
    const float* __restrict__ bias, ushort* __restrict__ fuse,
    ushort* __restrict__ qk_h) {
  const int lane = threadIdx.x & 63, wv = threadIdx.x >> 6;
  const int r = lane & 15, g = lane >> 4;
  const int row0 = blockIdx.x * 64 + wv * 16;
  const ushort* arh = Ah + (size_t)(row0 + r) * 256 + g * 8;
  f32x4 acc[16];
#pragma unroll
  for (int i = 0; i < 16; ++i) acc[i] = f32x4{0.f, 0.f, 0.f, 0.f};
#pragma unroll
  for (int kc = 0; kc < 8; ++kc) {
    short8 ah = *(const short8*)(arh + kc * 32);
    const ushort* bbh = Bh + r * 256 + kc * 32 + g * 8;
#pragma unroll
    for (int nt = 0; nt < 16; ++nt) {
      short8 bh = *(const short8*)(bbh + nt * 16 * 256);
      acc[nt] = mfma16(ah, bh, acc[nt]);
    }
  }
  const int qr = row0 + g * 4;
#pragma unroll
  for (int nt = 0; nt < 16; ++nt) {
    int n = nt * 16 + r;
    float bs = bias[n];
#pragma unroll
    for (int e = 0; e < 4; ++e) {
      float v = acc[nt][e] + bs;
      int q = qr + e;
      if (nt < 8) {
        int b = q / 49, p = q - b * 49;
        fuse[(size_t)b * IN_ + p * 256 + n] = f2bf(v);
      } else {
        qk_h[(size_t)q * 128 + (n - 128)] = f2bf(v * LOG2E);
      }
    }
  }
}

// S variant (n-split x2): nb==0 -> svT; nb==1 -> sk_h
__global__ __launch_bounds__(256) void gemm_conv_s(
    const ushort* __restrict__ Ah, const ushort* __restrict__ Bh,
    const float* __restrict__ bias, ushort* __restrict__ svT,
    ushort* __restrict__ sk_h) {
  const int lane = threadIdx.x & 63, wv = threadIdx.x >> 6;
  const int r = lane & 15, g = lane >> 4;
  const int row0 = blockIdx.x * 64 + wv * 16;
  const int nb = blockIdx.y;
  const ushort* arh = Ah + (size_t)(row0 + r) * 256 + g * 8;
  f32x4 acc[8];
#pragma unroll
  for (int i = 0; i < 8; ++i) acc[i] = f32x4{0.f, 0.f, 0.f, 0.f};
#pragma unroll
  for (int kc = 0; kc < 8; ++kc) {
    short8 ah = *(const short8*)(arh + kc * 32);
    const ushort* bbh = Bh + (size_t)(nb * 128 + r) * 256 + kc * 32 + g * 8;
#pragma unroll
    for (int nt = 0; nt < 8; ++nt) {
      short8 bh = *(const short8*)(bbh + nt * 16 * 256);
      acc[nt] = mfma16(ah, bh, acc[nt]);
    }
  }
  const int qr = row0 + g * 4;
#pragma unroll
  for (int nt = 0; nt < 8; ++nt) {
    int nl = nt * 16 + r;
    float bs = bias[nb * 128 + nl];
#pragma unroll
    for (int e = 0; e < 4; ++e) {
      float v = acc[nt][e] + bs;
      int k = qr + e;
      if (nb == 0) {
        svT[(size_t)nl * M_S + k] = f2bf(v);
      } else {
        sk_h[(size_t)k * 128 + nl] = f2bf(v);
      }
    }
  }
}

// ---------------- fused attention: dbuf LDS, 32 q-rows/wave (R9 geometry) -----
#define LOAD_TILE(T)                                                            \
  do {                                                                          \
    const int kb_ = (T) * 32;                                                   \
    pkh0 = *(const short8*)(Kh + (size_t)(kb_ + row0s) * 128 + c8s * 8);        \
    pkh1 = *(const short8*)(Kh + (size_t)(kb_ + row0s + 16) * 128 + c8s * 8);   \
    pv0  = *(const short8*)(Vt + (size_t)cvs * M_S + kb_ + kc2s * 8);           \
    pv1  = *(const short8*)(Vt + (size_t)(cvs + 64) * M_S + kb_ + kc2s * 8);    \
  } while (0)
#define PUBLISH(B)                                                              \
  do {                                                                          \
    *(short8*)(&khs[B][kloff0]) = pkh0;                                         \
    *(short8*)(&khs[B][kloff1]) = pkh1;                                         \
    *(short8*)(&vvs[B][voff0]) = pv0;                                           \
    *(short8*)(&vvs[B][voff1]) = pv1;                                           \
  } while (0)

__global__ __launch_bounds__(256) void attn_kernel(
    const ushort* __restrict__ Qh, const ushort* __restrict__ Kh,
    const ushort* __restrict__ Vt, float* __restrict__ pnum,
    float* __restrict__ pden) {
  __shared__ ushort khs[2][32 * KSTR];
  __shared__ ushort vvs[2][128 * 32];
  __shared__ ushort plds[4][16 * PSTR];
  const int tid = threadIdx.x;
  const int w = tid >> 6, lane = tid & 63;
  const int r = lane & 15, g = lane >> 4;
  const int q0 = blockIdx.x * 128 + w * 32;
  const int z = blockIdx.y;
  const int t0 = z * 24 + (z < 2 ? z : 2);
  const int tn = 24 + (z < 2 ? 1 : 0);
  ushort* pw = plds[w];

  const int row0s = tid >> 4, c8s = tid & 15;
  const int cvs = tid >> 2, kc2s = tid & 3;
  const int kloff0 = row0s * KSTR + c8s * 8;
  const int kloff1 = (row0s + 16) * KSTR + c8s * 8;
  const int voff0 = cvs * 32 + kc2s * 8;
  const int voff1 = (cvs + 64) * 32 + kc2s * 8;

  short8 aq[2][4];
#pragma unroll
  for (int mt = 0; mt < 2; ++mt)
#pragma unroll
    for (int kc = 0; kc < 4; ++kc)
      aq[mt][kc] = *(const short8*)(Qh + (size_t)(q0 + mt * 16 + r) * 128 + kc * 32 + g * 8);

  f32x4 acc[2][8];
#pragma unroll
  for (int mt = 0; mt < 2; ++mt)
#pragma unroll
    for (int ct = 0; ct < 8; ++ct) acc[mt][ct] = f32x4{0.f, 0.f, 0.f, 0.f};
  float den[2][4];
#pragma unroll
  for (int mt = 0; mt < 2; ++mt)
#pragma unroll
    for (int e = 0; e < 4; ++e) den[mt][e] = 0.f;

  short8 pkh0, pkh1, pv0, pv1;
  LOAD_TILE(t0);
  PUBLISH(0);
  if (tn > 1) LOAD_TILE(t0 + 1);
  __syncthreads();

  for (int i = 0; i < tn; ++i) {
    const int b = i & 1;
    if (i + 1 < tn) {
      PUBLISH(b ^ 1);                 // buf^1 last read at barrier ending i-1
      if (i + 2 < tn) LOAD_TILE(t0 + i + 2);
    }
    // ---- QK^T from LDS buf b (bf16 x bf16) ----
    f32x4 lg[2][2];
#pragma unroll
    for (int kt = 0; kt < 2; ++kt) {
      const int kbase = (kt * 16 + r) * KSTR;
      short8 bh[4];
#pragma unroll
      for (int kc = 0; kc < 4; ++kc)
        bh[kc] = *(const short8*)(&khs[b][kbase + (kc * 4 + g) * 8]);
#pragma unroll
      for (int mt = 0; mt < 2; ++mt) {
        f32x4 c = f32x4{0.f, 0.f, 0.f, 0.f};
#pragma unroll
        for (int kc = 0; kc < 4; ++kc)
          c = mfma16(aq[mt][kc], bh[kc], c);
        lg[mt][kt] = c;
      }
    }
    // ---- V fragments (mt-invariant) ----
    short8 vf[8];
#pragma unroll
    for (int ct = 0; ct < 8; ++ct)
      vf[ct] = *(const short8*)(&vvs[b][(ct * 16 + r) * 32 + g * 8]);
    // ---- per-mt: exp2 -> P (per-wave LDS slice) -> PV ----
#pragma unroll
    for (int mt = 0; mt < 2; ++mt) {
#pragma unroll
      for (int kt = 0; kt < 2; ++kt)
#pragma unroll
        for (int e = 0; e < 4; ++e) {
          float p = __builtin_amdgcn_exp2f(lg[mt][kt][e] - SHIFT2);
          den[mt][e] += p;
          pw[(g * 4 + e) * PSTR + kt * 16 + r] = f2bf_fast(p);
        }
      short8 pf = *(const short8*)(pw + r * PSTR + g * 8);
#pragma unroll
      for (int ct = 0; ct < 8; ++ct)
        acc[mt][ct] = mfma16(pf, vf[ct], acc[mt][ct]);
    }
    __syncthreads();
  }

#pragma unroll
  for (int mt = 0; mt < 2; ++mt)
#pragma unroll
    for (int e = 0; e < 4; ++e) {
      float d = den[mt][e];
      d += __shfl_xor(d, 1);
      d += __shfl_xor(d, 2);
      d += __shfl_xor(d, 4);
      d += __shfl_xor(d, 8);
      den[mt][e] = d;
    }
#pragma unroll
  for (int mt = 0; mt < 2; ++mt)
#pragma unroll
    for (int ct = 0; ct < 8; ++ct)
#pragma unroll
      for (int e = 0; e < 4; ++e) {
        int q = q0 + mt * 16 + g * 4 + e;
        int c = ct * 16 + r;
        pnum[((size_t)z * M_Q + q) * 128 + c] = acc[mt][ct][e];
      }
  if (r == 0) {
#pragma unroll
    for (int mt = 0; mt < 2; ++mt)
#pragma unroll
      for (int e = 0; e < 4; ++e)
        pden[(size_t)z * M_Q + q0 + mt * 16 + g * 4 + e] = den[mt][e];
  }
}

// combine key-split partials -> att half of fuse (token-major, coalesced)
__global__ void attn_reduce(const float* __restrict__ pnum, const float* __restrict__ pden,
                            ushort* __restrict__ fuse) {
  int idx = blockIdx.x * 256 + threadIdx.x;  // exactly 25088*32 (c-quads)
  int q = idx >> 5;
  int c4 = (idx & 31) * 4;
  float4 s = {0.f, 0.f, 0.f, 0.f};
  float d = 0.f;
#pragma unroll
  for (int z = 0; z < NZ; ++z) {
    float4 v = *(const float4*)(pnum + ((size_t)z * M_Q + q) * 128 + c4);
    s.x += v.x; s.y += v.y; s.z += v.z; s.w += v.w;
    d += pden[(size_t)z * M_Q + q];
  }
  float inv = 1.0f / d;
  int b = q / 49, p = q - b * 49;
  ushort4v o;
  o[0] = f2bf(s.x * inv); o[1] = f2bf(s.y * inv);
  o[2] = f2bf(s.z * inv); o[3] = f2bf(s.w * inv);
  *(ushort4v*)(fuse + (size_t)b * IN_ + p * 256 + 128 + c4) = o;
}

// ---------------- fc6: [512][12544] x W6p[2048][12544]^T bf16, K-split FZ=8 -----
// grid (32, 8) = 256 blocks; kz = bid&7 (XCD-local K-slice); W6p LDS-staged.
__global__ __launch_bounds__(256) void fc6_kernel(
    const ushort* __restrict__ fuse, const ushort* __restrict__ W6p,
    float* __restrict__ part) {
  __shared__ ushort wlds[2][64 * WSTR];
  const int lane = threadIdx.x & 63, wv = threadIdx.x >> 6;
  const int r = lane & 15, g = lane >> 4;
  const int m0 = wv * 128;
  const int kz = blockIdx.x & 7;
  const int nidx = (blockIdx.x >> 3) + 4 * blockIdx.y;   // [0,32)
  const int n0 = nidx * 64;
  const int k0 = kz * 1568;

  const int srow = threadIdx.x >> 2;          // 0..63
  const int skc  = (threadIdx.x & 3) * 8;     // 0,8,16,24
  const size_t wgbase = (size_t)(n0 + srow) * IN_ + k0 + skc;
  const int wloff = srow * WSTR + skc;

  f32x4 acc[8][4];
#pragma unroll
  for (int mt = 0; mt < 8; ++mt)
#pragma unroll
    for (int nt = 0; nt < 4; ++nt) acc[mt][nt] = f32x4{0.f, 0.f, 0.f, 0.f};

  short8 rA, rB;
  rA = *(const short8*)(W6p + wgbase);                 // slab 0
  *(short8*)(&wlds[0][wloff]) = rA;
  rA = *(const short8*)(W6p + wgbase + 32);            // slab 1
  rB = *(const short8*)(W6p + wgbase + 64);            // slab 2
  __syncthreads();

  for (int t = 0; t < 49; ++t) {
    const int b = t & 1;
    if (t + 1 < 49) {
      *(short8*)(&wlds[b ^ 1][wloff]) = rA;            // publish slab t+1
      rA = rB;
      if (t + 3 < 49) rB = *(const short8*)(W6p + wgbase + (size_t)(t + 3) * 32);
    }
    const int kcol = k0 + t * 32 + g * 8;
    short8 af[8];
#pragma unroll
    for (int mt = 0; mt < 8; ++mt)
      af[mt] = *(const short8*)(fuse + (size_t)(m0 + mt * 16 + r) * IN_ + kcol);
    short8 bfr[4];
#pragma unroll
    for (int nt = 0; nt < 4; ++nt)
      bfr[nt] = *(const short8*)(&wlds[b][(nt * 16 + r) * WSTR + g * 8]);
#pragma unroll
    for (int mt = 0; mt < 8; ++mt)
#pragma unroll
      for (int nt = 0; nt < 4; ++nt) acc[mt][nt] = mfma16(af[mt], bfr[nt], acc[mt][nt]);
    __syncthreads();
  }
#pragma unroll
  for (int mt = 0; mt < 8; ++mt)
#pragma unroll
    for (int nt = 0; nt < 4; ++nt)
#pragma unroll
      for (int e = 0; e < 4; ++e) {
        int m = m0 + mt * 16 + g * 4 + e;
        int n = n0 + nt * 16 + r;
        part[(size_t)kz * 1048576 + (size_t)m * 2048 + n] = acc[mt][nt][e];
      }
}

// sum split-K partials + bias + relu -> X7 bf16 [512][2048]
__global__ void fc6_reduce(const float* __restrict__ part, const float* __restrict__ b6c,
                           const float* __restrict__ b6r, ushort* __restrict__ X7) {
  int idx = blockIdx.x * 256 + threadIdx.x;  // exactly 512*2048
  int n = idx & 2047;
  float s = 0.f;
#pragma unroll
  for (int z = 0; z < FZ; ++z) s += part[(size_t)z * 1048576 + idx];
  s += (n < 1024) ? b6c[n] : b6r[n - 1024];
  s = fmaxf(s, 0.f);
  X7[idx] = f2bf(s);
}

// ---------------- fc7: [512][1024] x W7p[2048][1024]^T bf16 per half ------------
// n-split x2: each wave 16 rows x 32 n (acc[2]); grid (16, 64) = 1024 blocks.
__global__ __launch_bounds__(128) void fc7_kernel(
    const ushort* __restrict__ X7, const ushort* __restrict__ W7p,
    const float* __restrict__ b7c, const float* __restrict__ b7r,
    float* __restrict__ out) {
  const int lane = threadIdx.x & 63, wv = threadIdx.x >> 6;
  const int r = lane & 15, g = lane >> 4;
  const int m0 = blockIdx.x * 32 + wv * 16;
  const int n0 = blockIdx.y * 32;
  const int half = (n0 >= 1024) ? 1 : 0;
  const int nn0 = n0 - half * 1024;
  const float* b7 = half ? b7r : b7c;
  f32x4 acc[2];
#pragma unroll
  for (int nt = 0; nt < 2; ++nt) acc[nt] = f32x4{0.f, 0.f, 0.f, 0.f};
  const ushort* arow = X7 + (size_t)(m0 + r) * 2048 + half * 1024;
  for (int kk = 0; kk < 1024; kk += 32) {
    short8 a = *(const short8*)(arow + kk + g * 8);
#pragma unroll
    for (int nt = 0; nt < 2; ++nt) {
      short8 bb = *(const short8*)(W7p + (size_t)(half * 1024 + nn0 + nt * 16 + r) * 1024 + kk + g * 8);
      acc[nt] = mfma16(a, bb, acc[nt]);
    }
  }
  float* obase = out + (size_t)half * 524288;
#pragma unroll
  for (int nt = 0; nt < 2; ++nt) {
#pragma unroll
    for (int e = 0; e < 4; ++e) {
      int m = m0 + g * 4 + e;
      int n = nn0 + nt * 16 + r;
      obase[(size_t)m * 1024 + n] = fmaxf(acc[nt][e] + b7[n], 0.f);
    }
  }
}

// ---------------- launch ----------------
extern "C" void kernel_launch(void* const* d_in, const int* in_sizes, int n_in,
                              void* d_out, int out_size, void* d_ws, size_t ws_size,
                              hipStream_t stream) {
  const float* x    = (const float*)d_in[0];
  const float* sup  = (const float*)d_in[1];
  const float* Wqv  = (const float*)d_in[2];
  const float* bqv  = (const float*)d_in[3];
  const float* Wqk  = (const float*)d_in[4];
  const float* bqk  = (const float*)d_in[5];
  const float* Wsv  = (const float*)d_in[6];
  const float* bsv  = (const float*)d_in[7];
  const float* Wsk  = (const float*)d_in[8];
  const float* bsk  = (const float*)d_in[9];
  const float* W6c  = (const float*)d_in[10];
  const float* b6c  = (const float*)d_in[11];
  const float* W7c  = (const float*)d_in[12];
  const float* b7c  = (const float*)d_in[13];
  const float* W6r  = (const float*)d_in[14];
  const float* b6r  = (const float*)d_in[15];
  const float* W7r  = (const float*)d_in[16];
  const float* b7r  = (const float*)d_in[17];
  float* out = (float*)d_out;

  char* base = (char*)d_ws;
  size_t off = 0;
  auto alloc = [&](size_t bytes) {
    char* p = base + off;
    off += (bytes + 255) & ~(size_t)255;
    return p;
  };
  // Region A: stage 1 = Xp/Xs bf16 (14.5MB); stage 2 (after convs) = W6p+W7p (55.6MB)
  char* regionA = alloc((size_t)2048 * IN_ * 2 + (size_t)2048 * 1024 * 2);
  ushort* Xp_h = (ushort*)(regionA);
  ushort* Xs_h = (ushort*)(regionA + 12845056);
  ushort* W6p  = (ushort*)(regionA);
  ushort* W7p  = (ushort*)(regionA + (size_t)2048 * IN_ * 2);
  // Region B: attn pnum (51.4MB) then fc6 part (33.6MB)
  char* regionB = alloc((size_t)NZ * M_Q * 128 * 4);
  float* pnum = (float*)regionB;
  float* part = (float*)regionB;
  // Persistent region
  ushort* Wq_h = (ushort*)alloc(65536 * 2);
  ushort* Ws_h = (ushort*)alloc(65536 * 2);
  float*  biasq = (float*)alloc(256 * 4);
  float*  biass = (float*)alloc(256 * 4);
  ushort* fuse = (ushort*)alloc((size_t)512 * IN_ * 2);
  ushort* qk_h = (ushort*)alloc((size_t)M_Q * 128 * 2);
  ushort* sk_h = (ushort*)alloc((size_t)M_S * 128 * 2);
  ushort* svT  = (ushort*)alloc((size_t)M_S * 128 * 2);
  float*  pden = (float*)alloc((size_t)NZ * M_Q * 4);
  ushort* X7   = (ushort*)alloc((size_t)512 * 2048 * 2);
  if (off > ws_size) return;  // insufficient scratch; validation will show poison

  // 1) coalesced transpose+pack to bf16, token-major
  transpose_pack<<<dim3(512, 1, 4), dim3(256), 0, stream>>>(x, Xp_h, 49);
  transpose_pack<<<dim3(16, 4, 4), dim3(256), 0, stream>>>(sup, Xs_h, 196);
  pack_w<<<dim3(515), dim3(256), 0, stream>>>(Wqv, Wqk, bqv, bqk, Wsv, Wsk, bsv, bsk,
                                              Wq_h, biasq, Ws_h, biass);
  // 2) 1x1 convs (plain bf16 GEMM) with fused repack epilogues
  gemm_conv_q<<<dim3(392), dim3(256), 0, stream>>>(Xp_h, Wq_h, biasq, fuse, qk_h);
  gemm_conv_s<<<dim3(49, 2), dim3(256), 0, stream>>>(Xs_h, Ws_h, biass, svT, sk_h);
  // 3) pack MLP weights to bf16 into regionA (Xp/Xs now dead)
  pack_w6<<<dim3(2048), dim3(256), 0, stream>>>(W6c, W6r, W6p);
  pack_w7<<<dim3(8192), dim3(256), 0, stream>>>(W7c, W7r, W7p);
  // 4) fused attention (dbuf LDS, 32 q/wave, key-split) + combine
  attn_kernel<<<dim3(196, NZ), dim3(256), 0, stream>>>(qk_h, sk_h, svT, pnum, pden);
  attn_reduce<<<dim3(3136), dim3(256), 0, stream>>>(pnum, pden, fuse);
  // 5) fc6 (K-split, XCD-local kz, W6p LDS-staged) + reduce+relu
  fc6_kernel<<<dim3(32, FZ), dim3(256), 0, stream>>>(fuse, W6p, part);
  fc6_reduce<<<dim3(4096), dim3(256), 0, stream>>>(part, b6c, b6r, X7);
  // 6) fc7 + bias + relu -> d_out (xc then xr)
  fc7_kernel<<<dim3(16, 64), dim3(128), 0, stream>>>(X7, W7p, b7c, b7r, out);
}